// Round 1
// baseline (1430.281 us; speedup 1.0000x reference)
//
#include <hip/hip_runtime.h>
#include <hip/hip_bf16.h>

#define Bb 4
#define Tt 2048
#define Ccc 1024
#define HQn 16
#define HKVn 4
#define Dd 64
#define Gg 4

typedef unsigned short u16;
typedef short bf16x8 __attribute__((ext_vector_type(8)));
typedef float f32x4 __attribute__((ext_vector_type(4)));
static_assert(sizeof(bf16x8) == 16, "bf16x8 must be 16B");

static __device__ __forceinline__ u16 f2b(float f) {
  union { __hip_bfloat16 b; u16 u; } cv;
  cv.b = __float2bfloat16(f);
  return cv.u;
}

// ---------------- fp32 -> bf16 convert (vectorized) ----------------
__global__ void cvt_bf16(const float* __restrict__ in, u16* __restrict__ out, int n4) {
  int i = blockIdx.x * blockDim.x + threadIdx.x;
  if (i < n4) {
    float4 v = ((const float4*)in)[i];
    ushort4 o;
    o.x = f2b(v.x); o.y = f2b(v.y); o.z = f2b(v.z); o.w = f2b(v.w);
    ((ushort4*)out)[i] = o;
  }
}

// ---------------- fp32 [R][C] -> bf16 transposed [C][R] ----------------
__global__ void tpose(const float* __restrict__ in, u16* __restrict__ out, int R, int C) {
  __shared__ float tile[32][33];
  int c0 = blockIdx.x * 32, r0 = blockIdx.y * 32;
  int tx = threadIdx.x, ty = threadIdx.y;
  for (int i = ty; i < 32; i += 8)
    tile[i][tx] = in[(size_t)(r0 + i) * C + c0 + tx];
  __syncthreads();
  for (int i = ty; i < 32; i += 8)
    out[(size_t)(c0 + i) * R + r0 + tx] = f2b(tile[tx][i]);
}

// ---------------- bf16 V [B*T][HKV*D] -> Vt [B*HKV*D][T] ----------------
__global__ void vtrans(const u16* __restrict__ v, u16* __restrict__ vt) {
  __shared__ u16 tile[32][33];
  int bh = blockIdx.z;          // b*HKV + h
  int b = bh >> 2, h = bh & 3;
  int t0 = blockIdx.x * 32;
  int d0 = blockIdx.y * 32;
  int tx = threadIdx.x, ty = threadIdx.y;
  for (int i = ty; i < 32; i += 8)
    tile[i][tx] = v[(size_t)(b * Tt + t0 + i) * (HKVn * Dd) + h * Dd + d0 + tx];
  __syncthreads();
  for (int i = ty; i < 32; i += 8)
    vt[(size_t)(bh * Dd + d0 + i) * Tt + t0 + tx] = tile[tx][i];
}

// ---------------- bf16 GEMM: out = (A[M,K] * BT[N,K]^T + bias) * scale ----------------
// 128x128 block tile, 4 waves each 64x64, BK=32, mfma_f32_16x16x32_bf16
template <int OUT_BF16>
__global__ __launch_bounds__(256) void gemm_bf16(
    const u16* __restrict__ A, const u16* __restrict__ BT,
    const float* __restrict__ bias, void* __restrict__ out,
    int M, int N, int K, float scale) {
  __shared__ __align__(16) u16 As[128][40];
  __shared__ __align__(16) u16 Bs[128][40];
  const int tid = threadIdx.x;
  const int wave = tid >> 6, lane = tid & 63, l15 = lane & 15, quad = lane >> 4;
  const int m0 = blockIdx.y * 128, n0 = blockIdx.x * 128;
  const int wm = (wave >> 1) * 64, wn = (wave & 1) * 64;
  const int arow = tid >> 1, acol = (tid & 1) * 16;
  f32x4 acc[4][4] = {};
  for (int k0 = 0; k0 < K; k0 += 32) {
    bf16x8 av0 = *(const bf16x8*)(A + (size_t)(m0 + arow) * K + k0 + acol);
    bf16x8 av1 = *(const bf16x8*)(A + (size_t)(m0 + arow) * K + k0 + acol + 8);
    bf16x8 bv0 = *(const bf16x8*)(BT + (size_t)(n0 + arow) * K + k0 + acol);
    bf16x8 bv1 = *(const bf16x8*)(BT + (size_t)(n0 + arow) * K + k0 + acol + 8);
    *(bf16x8*)&As[arow][acol + 0] = av0;
    *(bf16x8*)&As[arow][acol + 8] = av1;
    *(bf16x8*)&Bs[arow][acol + 0] = bv0;
    *(bf16x8*)&Bs[arow][acol + 8] = bv1;
    __syncthreads();
    bf16x8 af[4], bfr[4];
#pragma unroll
    for (int i = 0; i < 4; ++i) af[i] = *(const bf16x8*)&As[wm + i * 16 + l15][quad * 8];
#pragma unroll
    for (int i = 0; i < 4; ++i) bfr[i] = *(const bf16x8*)&Bs[wn + i * 16 + l15][quad * 8];
#pragma unroll
    for (int i = 0; i < 4; ++i)
#pragma unroll
      for (int j = 0; j < 4; ++j)
        acc[i][j] = __builtin_amdgcn_mfma_f32_16x16x32_bf16(af[i], bfr[j], acc[i][j], 0, 0, 0);
    __syncthreads();
  }
#pragma unroll
  for (int i = 0; i < 4; ++i) {
    const int row = m0 + wm + i * 16 + quad * 4;
#pragma unroll
    for (int j = 0; j < 4; ++j) {
      const int col = n0 + wn + j * 16 + l15;
      const float bval = bias[col];
#pragma unroll
      for (int r = 0; r < 4; ++r) {
        float v = (acc[i][j][r] + bval) * scale;
        if (OUT_BF16)
          ((u16*)out)[(size_t)(row + r) * N + col] = f2b(v);
        else
          ((float*)out)[(size_t)(row + r) * N + col] = v;
      }
    }
  }
}

// ---------------- fused causal GQA attention ----------------
// grid: 1024 = B(4) * HKV(4) * G(4) * 16 q-tiles of 128 rows. 256 threads = 4 waves,
// wave w owns q rows [w*32, w*32+32). Two-pass flash: pass1 m/l, pass2 write P + PV.
__global__ __launch_bounds__(256) void attn(
    const u16* __restrict__ Q,   // [B*T][C], pre-scaled by 1/8
    const u16* __restrict__ K,   // [B*T][HKV*D]
    const u16* __restrict__ Vt,  // [B*HKV*D][T]
    float* __restrict__ att,     // [B,G,HKV,T,T]
    u16* __restrict__ Y) {       // [B*T][C] bf16
  __shared__ __align__(16) u16 Qs[128][72];
  __shared__ __align__(16) u16 Ks[64][72];
  __shared__ __align__(16) u16 Vs[64][72];   // Vs[d][k_local]
  __shared__ __align__(16) u16 Ps[128][72];

  const int bid = blockIdx.x;
  const int qt = bid & 15, g = (bid >> 4) & 3, h = (bid >> 6) & 3, b = bid >> 8;
  const int head = h * Gg + g;
  const int q0 = qt * 128;
  const int tid = threadIdx.x;
  const int wave = tid >> 6, lane = tid & 63, l15 = lane & 15, quad = lane >> 4;
  const int w32 = wave * 32;
  const int nkt = (q0 + 128) >> 6;  // k-tiles intersecting causal region

  {  // stage Q tile [128][64]
    const int row = tid >> 1, half = (tid & 1) * 32;
    const u16* src = Q + (size_t)(b * Tt + q0 + row) * Ccc + head * Dd + half;
    bf16x8 v0 = *(const bf16x8*)(src);
    bf16x8 v1 = *(const bf16x8*)(src + 8);
    bf16x8 v2 = *(const bf16x8*)(src + 16);
    bf16x8 v3 = *(const bf16x8*)(src + 24);
    *(bf16x8*)&Qs[row][half + 0]  = v0;
    *(bf16x8*)&Qs[row][half + 8]  = v1;
    *(bf16x8*)&Qs[row][half + 16] = v2;
    *(bf16x8*)&Qs[row][half + 24] = v3;
  }
  __syncthreads();

  float m_run[2][4], l_run[2][4];
#pragma unroll
  for (int ms = 0; ms < 2; ++ms)
#pragma unroll
    for (int r = 0; r < 4; ++r) { m_run[ms][r] = -1e30f; l_run[ms][r] = 0.f; }

  const int kkrow = tid >> 2, kpart = (tid & 3) * 16;

  // ---- pass 1: row max + sum ----
  for (int kt = 0; kt < nkt; ++kt) {
    const int k0 = kt * 64;
    {
      const u16* src = K + (size_t)(b * Tt + k0 + kkrow) * (HKVn * Dd) + h * Dd + kpart;
      bf16x8 v0 = *(const bf16x8*)(src);
      bf16x8 v1 = *(const bf16x8*)(src + 8);
      *(bf16x8*)&Ks[kkrow][kpart + 0] = v0;
      *(bf16x8*)&Ks[kkrow][kpart + 8] = v1;
    }
    __syncthreads();
    f32x4 s[2][4] = {};
#pragma unroll
    for (int c = 0; c < 2; ++c) {
      bf16x8 aq[2], bk[4];
#pragma unroll
      for (int ms = 0; ms < 2; ++ms)
        aq[ms] = *(const bf16x8*)&Qs[w32 + ms * 16 + l15][c * 32 + quad * 8];
#pragma unroll
      for (int ns = 0; ns < 4; ++ns)
        bk[ns] = *(const bf16x8*)&Ks[ns * 16 + l15][c * 32 + quad * 8];
#pragma unroll
      for (int ms = 0; ms < 2; ++ms)
#pragma unroll
        for (int ns = 0; ns < 4; ++ns)
          s[ms][ns] = __builtin_amdgcn_mfma_f32_16x16x32_bf16(aq[ms], bk[ns], s[ms][ns], 0, 0, 0);
    }
#pragma unroll
    for (int ms = 0; ms < 2; ++ms) {
#pragma unroll
      for (int r = 0; r < 4; ++r) {
        const int qg = q0 + w32 + ms * 16 + quad * 4 + r;
#pragma unroll
        for (int ns = 0; ns < 4; ++ns)
          if (k0 + ns * 16 + l15 > qg) s[ms][ns][r] = -1e30f;
        float tm = fmaxf(fmaxf(s[ms][0][r], s[ms][1][r]), fmaxf(s[ms][2][r], s[ms][3][r]));
#pragma unroll
        for (int off = 1; off < 16; off <<= 1)
          tm = fmaxf(tm, __shfl_xor(tm, off, 16));
        const float mnew = fmaxf(m_run[ms][r], tm);
        float ls = __expf(s[ms][0][r] - mnew) + __expf(s[ms][1][r] - mnew)
                 + __expf(s[ms][2][r] - mnew) + __expf(s[ms][3][r] - mnew);
#pragma unroll
        for (int off = 1; off < 16; off <<= 1)
          ls += __shfl_xor(ls, off, 16);
        l_run[ms][r] = l_run[ms][r] * __expf(m_run[ms][r] - mnew) + ls;
        m_run[ms][r] = mnew;
      }
    }
    __syncthreads();
  }

  float rl[2][4];
#pragma unroll
  for (int ms = 0; ms < 2; ++ms)
#pragma unroll
    for (int r = 0; r < 4; ++r) rl[ms][r] = 1.f / l_run[ms][r];

  f32x4 o[2][4] = {};
  const size_t att_base = ((size_t)((b * Gg + g) * HKVn + h)) * Tt * Tt;

  // ---- pass 2: recompute S, normalize, write att, accumulate P*V ----
  for (int kt = 0; kt < nkt; ++kt) {
    const int k0 = kt * 64;
    {
      const u16* src = K + (size_t)(b * Tt + k0 + kkrow) * (HKVn * Dd) + h * Dd + kpart;
      bf16x8 v0 = *(const bf16x8*)(src);
      bf16x8 v1 = *(const bf16x8*)(src + 8);
      const u16* vsrc = Vt + (size_t)((b * HKVn + h) * Dd + kkrow) * Tt + k0 + kpart;
      bf16x8 w0 = *(const bf16x8*)(vsrc);
      bf16x8 w1 = *(const bf16x8*)(vsrc + 8);
      *(bf16x8*)&Ks[kkrow][kpart + 0] = v0;
      *(bf16x8*)&Ks[kkrow][kpart + 8] = v1;
      *(bf16x8*)&Vs[kkrow][kpart + 0] = w0;
      *(bf16x8*)&Vs[kkrow][kpart + 8] = w1;
    }
    __syncthreads();
    f32x4 s[2][4] = {};
#pragma unroll
    for (int c = 0; c < 2; ++c) {
      bf16x8 aq[2], bk[4];
#pragma unroll
      for (int ms = 0; ms < 2; ++ms)
        aq[ms] = *(const bf16x8*)&Qs[w32 + ms * 16 + l15][c * 32 + quad * 8];
#pragma unroll
      for (int ns = 0; ns < 4; ++ns)
        bk[ns] = *(const bf16x8*)&Ks[ns * 16 + l15][c * 32 + quad * 8];
#pragma unroll
      for (int ms = 0; ms < 2; ++ms)
#pragma unroll
        for (int ns = 0; ns < 4; ++ns)
          s[ms][ns] = __builtin_amdgcn_mfma_f32_16x16x32_bf16(aq[ms], bk[ns], s[ms][ns], 0, 0, 0);
    }
#pragma unroll
    for (int ms = 0; ms < 2; ++ms) {
#pragma unroll
      for (int r = 0; r < 4; ++r) {
        const int qg = q0 + w32 + ms * 16 + quad * 4 + r;
#pragma unroll
        for (int ns = 0; ns < 4; ++ns) {
          const int kg = k0 + ns * 16 + l15;
          float p = (kg > qg) ? 0.f : __expf(s[ms][ns][r] - m_run[ms][r]) * rl[ms][r];
          att[att_base + (size_t)qg * Tt + kg] = p;
          Ps[w32 + ms * 16 + quad * 4 + r][ns * 16 + l15] = f2b(p);
        }
      }
    }
#pragma unroll
    for (int c = 0; c < 2; ++c) {
      bf16x8 ap[2], bv2[4];
#pragma unroll
      for (int ms = 0; ms < 2; ++ms)
        ap[ms] = *(const bf16x8*)&Ps[w32 + ms * 16 + l15][c * 32 + quad * 8];
#pragma unroll
      for (int nd = 0; nd < 4; ++nd)
        bv2[nd] = *(const bf16x8*)&Vs[nd * 16 + l15][c * 32 + quad * 8];
#pragma unroll
      for (int ms = 0; ms < 2; ++ms)
#pragma unroll
        for (int nd = 0; nd < 4; ++nd)
          o[ms][nd] = __builtin_amdgcn_mfma_f32_16x16x32_bf16(ap[ms], bv2[nd], o[ms][nd], 0, 0, 0);
    }
    __syncthreads();
  }

  // zero-fill the fully-masked upper-triangle region of att
  const int zstart = nkt * 64;  // == q0 + 128
  if (zstart < Tt) {
    const int zw4 = (Tt - zstart) >> 2;
    const float4 z4 = make_float4(0.f, 0.f, 0.f, 0.f);
    for (int rr = 0; rr < 128; ++rr) {
      float4* rowp = (float4*)(att + att_base + (size_t)(q0 + rr) * Tt + zstart);
      for (int cc = tid; cc < zw4; cc += 256) rowp[cc] = z4;
    }
  }

  // write O (already normalized) as bf16
#pragma unroll
  for (int ms = 0; ms < 2; ++ms)
#pragma unroll
    for (int nd = 0; nd < 4; ++nd)
#pragma unroll
      for (int r = 0; r < 4; ++r) {
        const int qg = q0 + w32 + ms * 16 + quad * 4 + r;
        Y[(size_t)(b * Tt + qg) * Ccc + head * Dd + nd * 16 + l15] = f2b(o[ms][nd][r]);
      }
}

extern "C" void kernel_launch(void* const* d_in, const int* in_sizes, int n_in,
                              void* d_out, int out_size, void* d_ws, size_t ws_size,
                              hipStream_t stream) {
  const float* x  = (const float*)d_in[0];
  const float* Wq = (const float*)d_in[1];
  const float* bq = (const float*)d_in[2];
  const float* Wk = (const float*)d_in[3];
  const float* bk = (const float*)d_in[4];
  const float* Wv = (const float*)d_in[5];
  const float* bv = (const float*)d_in[6];
  const float* Wo = (const float*)d_in[7];
  const float* bo = (const float*)d_in[8];
  float* out = (float*)d_out;

  char* ws = (char*)d_ws;
  u16* xb   = (u16*)(ws + 0);          // 16 MB : x bf16 [8192][1024]
  u16* WqT  = (u16*)(ws + 16777216);   // 2 MB  : Wq^T bf16 [1024][1024]
  u16* WkT  = (u16*)(ws + 18874368);   // 0.5 MB: Wk^T bf16 [256][1024]
  u16* WvT  = (u16*)(ws + 19398656);   // 0.5 MB
  u16* WoT  = (u16*)(ws + 19922944);   // 2 MB
  u16* Qb   = (u16*)(ws + 22020096);   // 16 MB : Q bf16 [8192][1024] (scaled 1/8)
  u16* Kb   = (u16*)(ws + 38797312);   // 4 MB  : K bf16 [8192][256]
  u16* Vb   = (u16*)(ws + 42991616);   // 4 MB
  u16* Vtb  = (u16*)(ws + 47185920);   // 4 MB  : V^T bf16 [B*HKV*64][2048]
  u16* Yatt = (u16*)(ws + 51380224);   // 16 MB : attention output bf16 [8192][1024]
  // total ws use: 68157440 bytes

  cvt_bf16<<<8192, 256, 0, stream>>>(x, xb, 8388608 / 4);
  tpose<<<dim3(32, 32), dim3(32, 8), 0, stream>>>(Wq, WqT, 1024, 1024);
  tpose<<<dim3(8, 32),  dim3(32, 8), 0, stream>>>(Wk, WkT, 1024, 256);
  tpose<<<dim3(8, 32),  dim3(32, 8), 0, stream>>>(Wv, WvT, 1024, 256);
  tpose<<<dim3(32, 32), dim3(32, 8), 0, stream>>>(Wo, WoT, 1024, 1024);

  gemm_bf16<1><<<dim3(8, 64), 256, 0, stream>>>(xb, WqT, bq, Qb, 8192, 1024, 1024, 0.125f);
  gemm_bf16<1><<<dim3(2, 64), 256, 0, stream>>>(xb, WkT, bk, Kb, 8192, 256, 1024, 1.0f);
  gemm_bf16<1><<<dim3(2, 64), 256, 0, stream>>>(xb, WvT, bv, Vb, 8192, 256, 1024, 1.0f);

  vtrans<<<dim3(64, 2, 16), dim3(32, 8), 0, stream>>>(Vb, Vtb);

  attn<<<1024, 256, 0, stream>>>(Qb, Kb, Vtb, out + 8388608, Yatt);

  gemm_bf16<0><<<dim3(8, 64), 256, 0, stream>>>(Yatt, WoT, bo, out, 8192, 1024, 1024, 1.0f);
}